// Round 1
// baseline (5959.434 us; speedup 1.0000x reference)
//
#include <hip/hip_runtime.h>
#include <math.h>

#define KNN 20
// 1/sqrt(1 + 1e-5)
#define BN_INV 0.9999950000374997f

__device__ __forceinline__ unsigned f2o(float f){
    unsigned u = __float_as_uint(f);
    return (u >> 31) ? ~u : (u | 0x80000000u);
}
__device__ __forceinline__ float o2f(unsigned u){
    return __uint_as_float((u >> 31) ? (u & 0x7fffffffu) : ~u);
}
__device__ __forceinline__ float leaky(float v){ return v > 0.f ? v : 0.2f * v; }

// Build feats[B,N,116] = [gfeat(14) | lbs(24) | pose(75) | pad0(3)]
__global__ __launch_bounds__(128) void build_feats_kernel(
    const float* __restrict__ xyz, const float* __restrict__ scale,
    const float* __restrict__ rot, const float* __restrict__ opac,
    const float* __restrict__ color, const float* __restrict__ pose,
    const float* __restrict__ lbs, float* __restrict__ feats, int N)
{
    int row = blockIdx.x;           // b*N + n
    int b = row / N, n = row % N;
    int c = threadIdx.x;            // 128 threads, write c<116
    float v;
    if      (c <   3) v = xyz  [n*3 + c];
    else if (c <   6) v = scale[n*3 + c-3];
    else if (c <  10) v = rot  [n*4 + c-6];
    else if (c <  11) v = opac [n];
    else if (c <  14) v = color[n*3 + c-11];
    else if (c <  38) v = lbs  [n*24 + c-14];
    else if (c < 113) v = pose [b*75 + c-38];
    else              v = 0.f;
    if (c < 116) feats[(long)row*116 + c] = v;
}

// kNN: one block per (b,i). Full distance row in LDS, 20 iterative argmax.
// x is [B,N,CP4*4] float4-aligned, zero-padded; requires N <= 4096.
__global__ __launch_bounds__(256) void knn_kernel(
    const float* __restrict__ x, int N, int CP4, int* __restrict__ idx_out)
{
    __shared__ float4 xi4[32];
    __shared__ float drow[4096];
    __shared__ float rv[4];
    __shared__ int   ri[4];

    int row = blockIdx.x;
    int b = row / N;
    int t = threadIdx.x;
    const float4* xp = (const float4*)x;

    if (t < CP4) xi4[t] = xp[(long)row * CP4 + t];
    __syncthreads();

    long bb = (long)b * N * CP4;
    for (int j = t; j < N; j += 256){
        const float4* p = xp + bb + (long)j * CP4;
        float acc = 0.f;
        #pragma unroll 4
        for (int c = 0; c < CP4; ++c){
            float4 xv = p[c], yv = xi4[c];
            float dx = xv.x - yv.x, dy = xv.y - yv.y;
            float dz = xv.z - yv.z, dw = xv.w - yv.w;
            acc += dx*dx + dy*dy + dz*dz + dw*dw;
        }
        drow[j] = -acc;  // neg squared distance; self = -0.0
    }
    __syncthreads();

    for (int it = 0; it < KNN; ++it){
        float bv = -INFINITY; int bi = N;
        for (int j = t; j < N; j += 256){
            float v = drow[j];
            if (v > bv){ bv = v; bi = j; }   // ascending j => smallest idx kept on tie
        }
        // wave butterfly argmax (64 lanes), tie-break smaller index
        #pragma unroll
        for (int off = 32; off > 0; off >>= 1){
            float ov = __shfl_xor(bv, off);
            int   oi = __shfl_xor(bi, off);
            if (ov > bv || (ov == bv && oi < bi)){ bv = ov; bi = oi; }
        }
        if ((t & 63) == 0){ rv[t >> 6] = bv; ri[t >> 6] = bi; }
        __syncthreads();
        if (t == 0){
            float fv = rv[0]; int fi = ri[0];
            #pragma unroll
            for (int w = 1; w < 4; ++w){
                if (rv[w] > fv || (rv[w] == fv && ri[w] < fi)){ fv = rv[w]; fi = ri[w]; }
            }
            idx_out[(long)row * KNN + it] = fi;
            drow[fi] = -INFINITY;
        }
        __syncthreads();
    }
}

// EdgeConv: y[row,d] = max_k leaky( (sum_c (x_j-x_i)*W[c,d] + sum_c x_i*W[C+c,d]) * g'+b )
// One block per (b,i), 256 threads. Thread owns channel d = t%D and KPT neighbors.
template<int D, int KPT>
__global__ __launch_bounds__(256) void edge_conv_kernel(
    const float* __restrict__ x, int N, int C, int CP,
    const float* __restrict__ W, const float* __restrict__ g,
    const float* __restrict__ bias, const int* __restrict__ idx,
    float* __restrict__ y)
{
    __shared__ float xi[128];
    __shared__ float nbr[KNN * 128];
    __shared__ float t2[D];
    __shared__ unsigned um[D];

    int row = blockIdx.x;
    int b = row / N;
    int t = threadIdx.x;

    for (int c = t; c < C; c += 256) xi[c] = x[(long)row * CP + c];
    for (int kk = 0; kk < KNN; ++kk){
        int j = idx[(long)row * KNN + kk];
        long nb = ((long)b * N + j) * CP;
        for (int c = t; c < C; c += 256) nbr[kk * C + c] = x[nb + c];
    }
    __syncthreads();

    // k-independent half: t2[d] = sum_c xi[c] * W[(C+c), d]
    for (int d = t; d < D; d += 256){
        float s = 0.f;
        for (int c = 0; c < C; ++c) s += xi[c] * W[(C + c) * D + d];
        t2[d] = s; um[d] = 0u;
    }
    __syncthreads();

    const int d  = t % D;
    const int kg = t / D;               // 0..TPD-1, TPD = 256/D
    float s[KPT];
    #pragma unroll
    for (int q = 0; q < KPT; ++q) s[q] = t2[d];

    const float* nb0 = &nbr[(kg * KPT) * C];
    for (int c = 0; c < C; ++c){
        float w   = W[c * D + d];
        float xic = xi[c];
        #pragma unroll
        for (int q = 0; q < KPT; ++q)
            s[q] += (nb0[q * C + c] - xic) * w;
    }
    float g_ = g[d] * BN_INV, b_ = bias[d];
    float m = -INFINITY;
    #pragma unroll
    for (int q = 0; q < KPT; ++q)
        m = fmaxf(m, leaky(s[q] * g_ + b_));
    atomicMax(&um[d], f2o(m));
    __syncthreads();

    for (int dd = t; dd < D; dd += 256)
        y[(long)row * D + dd] = o2f(um[dd]);
}

// Head: gf = leaky(BN(cat512 @ Wc5)); 2x { leaky(LN(h @ Wo + bo)) }; off = h @ Wo3 + bo3
// out[...,:14] += gfeat. One block per (b,i), 128 threads.
__global__ __launch_bounds__(128) void head_kernel(
    const float* __restrict__ x1, const float* __restrict__ x2,
    const float* __restrict__ x3, const float* __restrict__ x4,
    const float* __restrict__ feats,
    const float* __restrict__ Wc5, const float* __restrict__ g5, const float* __restrict__ b5,
    const float* __restrict__ Wo1, const float* __restrict__ bo1,
    const float* __restrict__ lg1, const float* __restrict__ lb1,
    const float* __restrict__ Wo2, const float* __restrict__ bo2,
    const float* __restrict__ lg2, const float* __restrict__ lb2,
    const float* __restrict__ Wo3, const float* __restrict__ bo3,
    float* __restrict__ out, int N)
{
    __shared__ float cat[512];
    __shared__ float a[128];
    __shared__ float red[128];
    __shared__ float stats[2];

    int row = blockIdx.x;
    int t = threadIdx.x;

    cat[t]       = (t < 64) ? x1[(long)row*64 + t] : x2[(long)row*64 + (t-64)];
    cat[128 + t] = x3[(long)row*128 + t];
    cat[256 + t] = x4[(long)row*256 + t];
    cat[384 + t] = x4[(long)row*256 + 128 + t];
    __syncthreads();

    // gf
    float s = 0.f;
    for (int c = 0; c < 512; ++c) s += cat[c] * Wc5[c*128 + t];
    a[t] = leaky(s * g5[t] * BN_INV + b5[t]);
    __syncthreads();

    // two LN-MLP layers
    for (int layer = 0; layer < 2; ++layer){
        const float* W  = layer ? Wo2 : Wo1;
        const float* bo = layer ? bo2 : bo1;
        const float* lg = layer ? lg2 : lg1;
        const float* lb = layer ? lb2 : lb1;
        s = bo[t];
        for (int c = 0; c < 128; ++c) s += a[c] * W[c*128 + t];
        // mean
        red[t] = s; __syncthreads();
        for (int st = 64; st > 0; st >>= 1){
            if (t < st) red[t] += red[t + st];
            __syncthreads();
        }
        if (t == 0) stats[0] = red[0] * (1.f/128.f);
        __syncthreads();
        float m = stats[0];
        float dm = s - m;
        red[t] = dm * dm; __syncthreads();
        for (int st = 64; st > 0; st >>= 1){
            if (t < st) red[t] += red[t + st];
            __syncthreads();
        }
        if (t == 0) stats[1] = red[0] * (1.f/128.f);
        __syncthreads();
        float var = stats[1];
        float hn = leaky(dm * rsqrtf(var + 1e-5f) * lg[t] + lb[t]);
        __syncthreads();          // everyone done reading a[] from prev layer
        a[t] = hn;
        __syncthreads();
    }

    if (t < 38){
        float o = bo3[t];
        for (int c = 0; c < 128; ++c) o += a[c] * Wo3[c*38 + t];
        if (t < 14) o += feats[(long)row*116 + t];
        out[(long)row*38 + t] = o;
    }
}

extern "C" void kernel_launch(void* const* d_in, const int* in_sizes, int n_in,
                              void* d_out, int out_size, void* d_ws, size_t ws_size,
                              hipStream_t stream)
{
    const float* xyz  = (const float*)d_in[0];
    const float* scal = (const float*)d_in[1];
    const float* rot  = (const float*)d_in[2];
    const float* opac = (const float*)d_in[3];
    const float* colr = (const float*)d_in[4];
    const float* pose = (const float*)d_in[5];
    const float* lbs  = (const float*)d_in[6];
    const float* Wc1 = (const float*)d_in[7];  const float* g1 = (const float*)d_in[8];  const float* b1 = (const float*)d_in[9];
    const float* Wc2 = (const float*)d_in[10]; const float* g2 = (const float*)d_in[11]; const float* b2 = (const float*)d_in[12];
    const float* Wc3 = (const float*)d_in[13]; const float* g3 = (const float*)d_in[14]; const float* b3 = (const float*)d_in[15];
    const float* Wc4 = (const float*)d_in[16]; const float* g4 = (const float*)d_in[17]; const float* b4 = (const float*)d_in[18];
    const float* Wc5 = (const float*)d_in[19]; const float* g5 = (const float*)d_in[20]; const float* b5 = (const float*)d_in[21];
    const float* Wo1 = (const float*)d_in[22]; const float* bo1 = (const float*)d_in[23];
    const float* lg1 = (const float*)d_in[24]; const float* lb1 = (const float*)d_in[25];
    const float* Wo2 = (const float*)d_in[26]; const float* bo2 = (const float*)d_in[27];
    const float* lg2 = (const float*)d_in[28]; const float* lb2 = (const float*)d_in[29];
    const float* Wo3 = (const float*)d_in[30]; const float* bo3 = (const float*)d_in[31];

    const int N = in_sizes[0] / 3;      // 4096
    const int B = in_sizes[5] / 75;     // 2
    const int R = B * N;

    char* ws = (char*)d_ws;
    size_t o = 0;
    float* feats = (float*)(ws + o); o += (size_t)R * 116 * 4;
    float* x1    = (float*)(ws + o); o += (size_t)R * 64  * 4;
    float* x2    = (float*)(ws + o); o += (size_t)R * 64  * 4;
    float* x3    = (float*)(ws + o); o += (size_t)R * 128 * 4;
    float* x4    = (float*)(ws + o); o += (size_t)R * 256 * 4;
    int*   idx   = (int*)  (ws + o); o += (size_t)R * KNN * 4;

    build_feats_kernel<<<R, 128, 0, stream>>>(xyz, scal, rot, opac, colr, pose, lbs, feats, N);

    knn_kernel<<<R, 256, 0, stream>>>(feats, N, 116/4, idx);
    edge_conv_kernel<64, 5><<<R, 256, 0, stream>>>(feats, N, 113, 116, Wc1, g1, b1, idx, x1);

    knn_kernel<<<R, 256, 0, stream>>>(x1, N, 64/4, idx);
    edge_conv_kernel<64, 5><<<R, 256, 0, stream>>>(x1, N, 64, 64, Wc2, g2, b2, idx, x2);

    knn_kernel<<<R, 256, 0, stream>>>(x2, N, 64/4, idx);
    edge_conv_kernel<128, 10><<<R, 256, 0, stream>>>(x2, N, 64, 64, Wc3, g3, b3, idx, x3);

    knn_kernel<<<R, 256, 0, stream>>>(x3, N, 128/4, idx);
    edge_conv_kernel<256, 20><<<R, 256, 0, stream>>>(x3, N, 128, 128, Wc4, g4, b4, idx, x4);

    head_kernel<<<R, 128, 0, stream>>>(x1, x2, x3, x4, feats,
                                       Wc5, g5, b5, Wo1, bo1, lg1, lb1,
                                       Wo2, bo2, lg2, lb2, Wo3, bo3,
                                       (float*)d_out, N);
}

// Round 2
// 1658.635 us; speedup vs baseline: 3.5930x; 3.5930x over previous
//
#include <hip/hip_runtime.h>
#include <math.h>

#define KNN 20
// 1/sqrt(1 + 1e-5)
#define BN_INV 0.9999950000374997f

__device__ __forceinline__ unsigned f2o(float f){
    unsigned u = __float_as_uint(f);
    return (u >> 31) ? ~u : (u | 0x80000000u);
}
__device__ __forceinline__ float o2f(unsigned u){
    return __uint_as_float((u >> 31) ? (u & 0x7fffffffu) : ~u);
}
__device__ __forceinline__ float leaky(float v){ return v > 0.f ? v : 0.2f * v; }

// Build feats[B,N,116] = [gfeat(14) | lbs(24) | pose(75) | pad0(3)]; also sq[row]
__global__ __launch_bounds__(128) void build_feats_kernel(
    const float* __restrict__ xyz, const float* __restrict__ scale,
    const float* __restrict__ rot, const float* __restrict__ opac,
    const float* __restrict__ color, const float* __restrict__ pose,
    const float* __restrict__ lbs, float* __restrict__ feats,
    float* __restrict__ sqout, int N)
{
    __shared__ float sred[2];
    int row = blockIdx.x;           // b*N + n
    int b = row / N, n = row % N;
    int c = threadIdx.x;            // 128 threads, write c<116
    float v = 0.f;
    if      (c <   3) v = xyz  [n*3 + c];
    else if (c <   6) v = scale[n*3 + c-3];
    else if (c <  10) v = rot  [n*4 + c-6];
    else if (c <  11) v = opac [n];
    else if (c <  14) v = color[n*3 + c-11];
    else if (c <  38) v = lbs  [n*24 + c-14];
    else if (c < 113) v = pose [b*75 + c-38];
    if (c < 116) feats[(long)row*116 + c] = v;
    float ss = v * v;
    #pragma unroll
    for (int off = 32; off; off >>= 1) ss += __shfl_xor(ss, off);
    if ((c & 63) == 0) sred[c >> 6] = ss;
    __syncthreads();
    if (c == 0) sqout[row] = sred[0] + sred[1];
}

// ---------------- fast kNN path: Gram matrix + register top-k ----------------

// G[b][i][j] = sum_c x[b,i,c]*x[b,j,c].  128x128 tile per block, 8x8 per thread.
// LDS tiles [128][68] (stride 68 = 4 mod 8 -> worst 2-way bank alias, free).
template<int C>
__global__ __launch_bounds__(256) void dist_gemm_kernel(
    const float* __restrict__ x, int N, int CP, float* __restrict__ G)
{
    __shared__ __align__(16) float xi[128][68];
    __shared__ __align__(16) float xj[128][68];
    const int b  = blockIdx.z;
    const int bi = blockIdx.x * 128;
    const int bj = blockIdx.y * 128;
    const int t  = threadIdx.x;
    const int tx = t & 15, ty = t >> 4;
    const int CP4 = CP / 4;
    const long base = (long)b * N;
    const float4* xp = (const float4*)x;

    float acc[8][8] = {};

    for (int c0 = 0; c0 < C; c0 += 64){
        const int KCc = (C - c0 < 64) ? (C - c0) : 64;
        const int KC4 = KCc >> 2;
        __syncthreads();
        for (int f = t; f < 128 * KC4; f += 256){
            int r = f / KC4, c4 = f - r * KC4;
            float4 a = xp[(base + bi + r) * CP4 + (c0 >> 2) + c4];
            float4 bv = xp[(base + bj + r) * CP4 + (c0 >> 2) + c4];
            *(float4*)&xi[r][c4 * 4] = a;
            *(float4*)&xj[r][c4 * 4] = bv;
        }
        __syncthreads();
        for (int c = 0; c < KCc; c += 4){
            float4 A[8], Bv[8];
            #pragma unroll
            for (int ii = 0; ii < 8; ++ii) A[ii]  = *(const float4*)&xi[ty + 16*ii][c];
            #pragma unroll
            for (int jj = 0; jj < 8; ++jj) Bv[jj] = *(const float4*)&xj[tx + 16*jj][c];
            #pragma unroll
            for (int ii = 0; ii < 8; ++ii)
                #pragma unroll
                for (int jj = 0; jj < 8; ++jj){
                    acc[ii][jj] = fmaf(A[ii].x, Bv[jj].x, acc[ii][jj]);
                    acc[ii][jj] = fmaf(A[ii].y, Bv[jj].y, acc[ii][jj]);
                    acc[ii][jj] = fmaf(A[ii].z, Bv[jj].z, acc[ii][jj]);
                    acc[ii][jj] = fmaf(A[ii].w, Bv[jj].w, acc[ii][jj]);
                }
        }
    }

    #pragma unroll
    for (int ii = 0; ii < 8; ++ii){
        long rbase = (base + bi + ty + 16*ii) * N + bj;
        #pragma unroll
        for (int jj = 0; jj < 8; ++jj)
            G[rbase + tx + 16*jj] = acc[ii][jj];
    }
}

// Per-row top-20 by v_j = 2*G[i][j] - sq[j] (order == reference's 2G-sqi-sqj).
// 4096 candidates in registers (16/thread), butterfly argmax, tie -> smaller j.
__global__ __launch_bounds__(256) void topk_kernel(
    const float* __restrict__ G, const float* __restrict__ sq,
    int N, int* __restrict__ idx_out)
{
    __shared__ float wv_[4];
    __shared__ int   wj_[4];
    __shared__ int   gj_;
    const int row = blockIdx.x;
    const int b   = row / N;
    const int t   = threadIdx.x;
    const float* g   = G  + (long)row * N;
    const float* sqb = sq + (long)b * N;

    float v[16];
    #pragma unroll
    for (int q = 0; q < 16; ++q){
        int j = t + 256 * q;
        v[q] = fmaf(2.f, g[j], -sqb[j]);
    }
    float lv = v[0]; int lj = t;
    #pragma unroll
    for (int q = 1; q < 16; ++q)
        if (v[q] > lv){ lv = v[q]; lj = t + 256 * q; }

    for (int it = 0; it < KNN; ++it){
        float bv = lv; int bj = lj;
        #pragma unroll
        for (int off = 32; off; off >>= 1){
            float ov = __shfl_xor(bv, off);
            int   oj = __shfl_xor(bj, off);
            if (ov > bv || (ov == bv && oj < bj)){ bv = ov; bj = oj; }
        }
        if ((t & 63) == 0){ wv_[t >> 6] = bv; wj_[t >> 6] = bj; }
        __syncthreads();
        if (t == 0){
            float fv = wv_[0]; int fj = wj_[0];
            #pragma unroll
            for (int w = 1; w < 4; ++w)
                if (wv_[w] > fv || (wv_[w] == fv && wj_[w] < fj)){ fv = wv_[w]; fj = wj_[w]; }
            gj_ = fj;
            idx_out[(long)row * KNN + it] = fj;
        }
        __syncthreads();
        int fj = gj_;
        if ((fj & 255) == t){
            int q = fj >> 8;
            #pragma unroll
            for (int qq = 0; qq < 16; ++qq)
                if (qq == q) v[qq] = -INFINITY;
            lv = v[0]; lj = t;
            #pragma unroll
            for (int qq = 1; qq < 16; ++qq)
                if (v[qq] > lv){ lv = v[qq]; lj = t + 256 * qq; }
        }
    }
}

// ---------------- fallback kNN (previous round, known-good) ----------------
__global__ __launch_bounds__(256) void knn_kernel(
    const float* __restrict__ x, int N, int CP4, int* __restrict__ idx_out)
{
    __shared__ float4 xi4[32];
    __shared__ float drow[4096];
    __shared__ float rv[4];
    __shared__ int   ri[4];

    int row = blockIdx.x;
    int b = row / N;
    int t = threadIdx.x;
    const float4* xp = (const float4*)x;

    if (t < CP4) xi4[t] = xp[(long)row * CP4 + t];
    __syncthreads();

    long bb = (long)b * N * CP4;
    for (int j = t; j < N; j += 256){
        const float4* p = xp + bb + (long)j * CP4;
        float acc = 0.f;
        #pragma unroll 4
        for (int c = 0; c < CP4; ++c){
            float4 xv = p[c], yv = xi4[c];
            float dx = xv.x - yv.x, dy = xv.y - yv.y;
            float dz = xv.z - yv.z, dw = xv.w - yv.w;
            acc += dx*dx + dy*dy + dz*dz + dw*dw;
        }
        drow[j] = -acc;
    }
    __syncthreads();

    for (int it = 0; it < KNN; ++it){
        float bv = -INFINITY; int bi = N;
        for (int j = t; j < N; j += 256){
            float v = drow[j];
            if (v > bv){ bv = v; bi = j; }
        }
        #pragma unroll
        for (int off = 32; off > 0; off >>= 1){
            float ov = __shfl_xor(bv, off);
            int   oi = __shfl_xor(bi, off);
            if (ov > bv || (ov == bv && oi < bi)){ bv = ov; bi = oi; }
        }
        if ((t & 63) == 0){ rv[t >> 6] = bv; ri[t >> 6] = bi; }
        __syncthreads();
        if (t == 0){
            float fv = rv[0]; int fi = ri[0];
            #pragma unroll
            for (int w = 1; w < 4; ++w){
                if (rv[w] > fv || (rv[w] == fv && ri[w] < fi)){ fv = rv[w]; fi = ri[w]; }
            }
            idx_out[(long)row * KNN + it] = fi;
            drow[fi] = -INFINITY;
        }
        __syncthreads();
    }
}

// EdgeConv + fused sq of output row.
template<int D, int KPT>
__global__ __launch_bounds__(256) void edge_conv_kernel(
    const float* __restrict__ x, int N, int C, int CP,
    const float* __restrict__ W, const float* __restrict__ g,
    const float* __restrict__ bias, const int* __restrict__ idx,
    float* __restrict__ y, float* __restrict__ sqout)
{
    __shared__ float xi[128];
    __shared__ float nbr[KNN * 128];
    __shared__ float t2[D];
    __shared__ unsigned um[D];
    __shared__ float sred[4];

    int row = blockIdx.x;
    int b = row / N;
    int t = threadIdx.x;

    for (int c = t; c < C; c += 256) xi[c] = x[(long)row * CP + c];
    for (int kk = 0; kk < KNN; ++kk){
        int j = idx[(long)row * KNN + kk];
        long nb = ((long)b * N + j) * CP;
        for (int c = t; c < C; c += 256) nbr[kk * C + c] = x[nb + c];
    }
    __syncthreads();

    for (int d = t; d < D; d += 256){
        float s = 0.f;
        for (int c = 0; c < C; ++c) s += xi[c] * W[(C + c) * D + d];
        t2[d] = s; um[d] = 0u;
    }
    __syncthreads();

    const int d  = t % D;
    const int kg = t / D;
    float s[KPT];
    #pragma unroll
    for (int q = 0; q < KPT; ++q) s[q] = t2[d];

    const float* nb0 = &nbr[(kg * KPT) * C];
    for (int c = 0; c < C; ++c){
        float w   = W[c * D + d];
        float xic = xi[c];
        #pragma unroll
        for (int q = 0; q < KPT; ++q)
            s[q] += (nb0[q * C + c] - xic) * w;
    }
    float g_ = g[d] * BN_INV, b_ = bias[d];
    float m = -INFINITY;
    #pragma unroll
    for (int q = 0; q < KPT; ++q)
        m = fmaxf(m, leaky(s[q] * g_ + b_));
    atomicMax(&um[d], f2o(m));
    __syncthreads();

    float ss = 0.f;
    for (int dd = t; dd < D; dd += 256){
        float val = o2f(um[dd]);
        y[(long)row * D + dd] = val;
        ss += val * val;
    }
    #pragma unroll
    for (int off = 32; off; off >>= 1) ss += __shfl_xor(ss, off);
    if ((t & 63) == 0) sred[t >> 6] = ss;
    __syncthreads();
    if (t == 0) sqout[row] = sred[0] + sred[1] + sred[2] + sred[3];
}

// Head (unchanged)
__global__ __launch_bounds__(128) void head_kernel(
    const float* __restrict__ x1, const float* __restrict__ x2,
    const float* __restrict__ x3, const float* __restrict__ x4,
    const float* __restrict__ feats,
    const float* __restrict__ Wc5, const float* __restrict__ g5, const float* __restrict__ b5,
    const float* __restrict__ Wo1, const float* __restrict__ bo1,
    const float* __restrict__ lg1, const float* __restrict__ lb1,
    const float* __restrict__ Wo2, const float* __restrict__ bo2,
    const float* __restrict__ lg2, const float* __restrict__ lb2,
    const float* __restrict__ Wo3, const float* __restrict__ bo3,
    float* __restrict__ out, int N)
{
    __shared__ float cat[512];
    __shared__ float a[128];
    __shared__ float red[128];
    __shared__ float stats[2];

    int row = blockIdx.x;
    int t = threadIdx.x;

    cat[t]       = (t < 64) ? x1[(long)row*64 + t] : x2[(long)row*64 + (t-64)];
    cat[128 + t] = x3[(long)row*128 + t];
    cat[256 + t] = x4[(long)row*256 + t];
    cat[384 + t] = x4[(long)row*256 + 128 + t];
    __syncthreads();

    float s = 0.f;
    for (int c = 0; c < 512; ++c) s += cat[c] * Wc5[c*128 + t];
    a[t] = leaky(s * g5[t] * BN_INV + b5[t]);
    __syncthreads();

    for (int layer = 0; layer < 2; ++layer){
        const float* W  = layer ? Wo2 : Wo1;
        const float* bo = layer ? bo2 : bo1;
        const float* lg = layer ? lg2 : lg1;
        const float* lb = layer ? lb2 : lb1;
        s = bo[t];
        for (int c = 0; c < 128; ++c) s += a[c] * W[c*128 + t];
        red[t] = s; __syncthreads();
        for (int st = 64; st > 0; st >>= 1){
            if (t < st) red[t] += red[t + st];
            __syncthreads();
        }
        if (t == 0) stats[0] = red[0] * (1.f/128.f);
        __syncthreads();
        float m = stats[0];
        float dm = s - m;
        red[t] = dm * dm; __syncthreads();
        for (int st = 64; st > 0; st >>= 1){
            if (t < st) red[t] += red[t + st];
            __syncthreads();
        }
        if (t == 0) stats[1] = red[0] * (1.f/128.f);
        __syncthreads();
        float var = stats[1];
        float hn = leaky(dm * rsqrtf(var + 1e-5f) * lg[t] + lb[t]);
        __syncthreads();
        a[t] = hn;
        __syncthreads();
    }

    if (t < 38){
        float o = bo3[t];
        for (int c = 0; c < 128; ++c) o += a[c] * Wo3[c*38 + t];
        if (t < 14) o += feats[(long)row*116 + t];
        out[(long)row*38 + t] = o;
    }
}

extern "C" void kernel_launch(void* const* d_in, const int* in_sizes, int n_in,
                              void* d_out, int out_size, void* d_ws, size_t ws_size,
                              hipStream_t stream)
{
    const float* xyz  = (const float*)d_in[0];
    const float* scal = (const float*)d_in[1];
    const float* rot  = (const float*)d_in[2];
    const float* opac = (const float*)d_in[3];
    const float* colr = (const float*)d_in[4];
    const float* pose = (const float*)d_in[5];
    const float* lbs  = (const float*)d_in[6];
    const float* Wc1 = (const float*)d_in[7];  const float* g1 = (const float*)d_in[8];  const float* b1 = (const float*)d_in[9];
    const float* Wc2 = (const float*)d_in[10]; const float* g2 = (const float*)d_in[11]; const float* b2 = (const float*)d_in[12];
    const float* Wc3 = (const float*)d_in[13]; const float* g3 = (const float*)d_in[14]; const float* b3 = (const float*)d_in[15];
    const float* Wc4 = (const float*)d_in[16]; const float* g4 = (const float*)d_in[17]; const float* b4 = (const float*)d_in[18];
    const float* Wc5 = (const float*)d_in[19]; const float* g5 = (const float*)d_in[20]; const float* b5 = (const float*)d_in[21];
    const float* Wo1 = (const float*)d_in[22]; const float* bo1 = (const float*)d_in[23];
    const float* lg1 = (const float*)d_in[24]; const float* lb1 = (const float*)d_in[25];
    const float* Wo2 = (const float*)d_in[26]; const float* bo2 = (const float*)d_in[27];
    const float* lg2 = (const float*)d_in[28]; const float* lb2 = (const float*)d_in[29];
    const float* Wo3 = (const float*)d_in[30]; const float* bo3 = (const float*)d_in[31];

    const int N = in_sizes[0] / 3;      // 4096
    const int B = in_sizes[5] / 75;     // 2
    const int R = B * N;

    char* ws = (char*)d_ws;
    size_t o = 0;
    float* feats = (float*)(ws + o); o += (size_t)R * 116 * 4;
    float* x1    = (float*)(ws + o); o += (size_t)R * 64  * 4;
    float* x2    = (float*)(ws + o); o += (size_t)R * 64  * 4;
    float* x3    = (float*)(ws + o); o += (size_t)R * 128 * 4;
    float* x4    = (float*)(ws + o); o += (size_t)R * 256 * 4;
    int*   idx   = (int*)  (ws + o); o += (size_t)R * KNN * 4;
    float* sq    = (float*)(ws + o); o += (size_t)R * 4;
    float* G     = (float*)(ws + o);
    size_t need  = o + (size_t)B * N * N * 4;

    const bool fast = (N == 4096) && (ws_size >= need);

    build_feats_kernel<<<R, 128, 0, stream>>>(xyz, scal, rot, opac, colr, pose, lbs, feats, sq, N);

    if (fast){
        dim3 gg(N/128, N/128, B);
        dist_gemm_kernel<116><<<gg, 256, 0, stream>>>(feats, N, 116, G);
        topk_kernel<<<R, 256, 0, stream>>>(G, sq, N, idx);
        edge_conv_kernel<64, 5><<<R, 256, 0, stream>>>(feats, N, 113, 116, Wc1, g1, b1, idx, x1, sq);

        dist_gemm_kernel<64><<<gg, 256, 0, stream>>>(x1, N, 64, G);
        topk_kernel<<<R, 256, 0, stream>>>(G, sq, N, idx);
        edge_conv_kernel<64, 5><<<R, 256, 0, stream>>>(x1, N, 64, 64, Wc2, g2, b2, idx, x2, sq);

        dist_gemm_kernel<64><<<gg, 256, 0, stream>>>(x2, N, 64, G);
        topk_kernel<<<R, 256, 0, stream>>>(G, sq, N, idx);
        edge_conv_kernel<128, 10><<<R, 256, 0, stream>>>(x2, N, 64, 64, Wc3, g3, b3, idx, x3, sq);

        dist_gemm_kernel<128><<<gg, 256, 0, stream>>>(x3, N, 128, G);
        topk_kernel<<<R, 256, 0, stream>>>(G, sq, N, idx);
        edge_conv_kernel<256, 20><<<R, 256, 0, stream>>>(x3, N, 128, Wc4 ? 128 : 128, Wc4, g4, b4, idx, x4, sq);
    } else {
        knn_kernel<<<R, 256, 0, stream>>>(feats, N, 116/4, idx);
        edge_conv_kernel<64, 5><<<R, 256, 0, stream>>>(feats, N, 113, 116, Wc1, g1, b1, idx, x1, sq);
        knn_kernel<<<R, 256, 0, stream>>>(x1, N, 64/4, idx);
        edge_conv_kernel<64, 5><<<R, 256, 0, stream>>>(x1, N, 64, 64, Wc2, g2, b2, idx, x2, sq);
        knn_kernel<<<R, 256, 0, stream>>>(x2, N, 64/4, idx);
        edge_conv_kernel<128, 10><<<R, 256, 0, stream>>>(x2, N, 64, 64, Wc3, g3, b3, idx, x3, sq);
        knn_kernel<<<R, 256, 0, stream>>>(x3, N, 128/4, idx);
        edge_conv_kernel<256, 20><<<R, 256, 0, stream>>>(x3, N, 128, 128, Wc4, g4, b4, idx, x4, sq);
    }

    head_kernel<<<R, 128, 0, stream>>>(x1, x2, x3, x4, feats,
                                       Wc5, g5, b5, Wo1, bo1, lg1, lb1,
                                       Wo2, bo2, lg2, lb2, Wo3, bo3,
                                       (float*)d_out, N);
}

// Round 3
// 1159.559 us; speedup vs baseline: 5.1394x; 1.4304x over previous
//
#include <hip/hip_runtime.h>
#include <math.h>

#define KNN 20
// 1/sqrt(1 + 1e-5)
#define BN_INV 0.9999950000374997f

__device__ __forceinline__ unsigned f2o(float f){
    unsigned u = __float_as_uint(f);
    return (u >> 31) ? ~u : (u | 0x80000000u);
}
__device__ __forceinline__ float o2f(unsigned u){
    return __uint_as_float((u >> 31) ? (u & 0x7fffffffu) : ~u);
}
__device__ __forceinline__ float leaky(float v){ return v > 0.f ? v : 0.2f * v; }

// Build feats[B,N,116] = [gfeat(14) | lbs(24) | pose(75) | pad0(3)]; also sq[row]
__global__ __launch_bounds__(128) void build_feats_kernel(
    const float* __restrict__ xyz, const float* __restrict__ scale,
    const float* __restrict__ rot, const float* __restrict__ opac,
    const float* __restrict__ color, const float* __restrict__ pose,
    const float* __restrict__ lbs, float* __restrict__ feats,
    float* __restrict__ sqout, int N)
{
    __shared__ float sred[2];
    int row = blockIdx.x;           // b*N + n
    int b = row / N, n = row % N;
    int c = threadIdx.x;            // 128 threads, write c<116
    float v = 0.f;
    if      (c <   3) v = xyz  [n*3 + c];
    else if (c <   6) v = scale[n*3 + c-3];
    else if (c <  10) v = rot  [n*4 + c-6];
    else if (c <  11) v = opac [n];
    else if (c <  14) v = color[n*3 + c-11];
    else if (c <  38) v = lbs  [n*24 + c-14];
    else if (c < 113) v = pose [b*75 + c-38];
    if (c < 116) feats[(long)row*116 + c] = v;
    float ss = v * v;
    #pragma unroll
    for (int off = 32; off; off >>= 1) ss += __shfl_xor(ss, off);
    if ((c & 63) == 0) sred[c >> 6] = ss;
    __syncthreads();
    if (c == 0) sqout[row] = sred[0] + sred[1];
}

// ---------------- kNN: Gram matrix + register top-k ----------------

// G[b][i][j] = sum_c x[b,i,c]*x[b,j,c].  128x128 tile per block, 8x8 per thread.
template<int C>
__global__ __launch_bounds__(256) void dist_gemm_kernel(
    const float* __restrict__ x, int N, int CP, float* __restrict__ G)
{
    __shared__ __align__(16) float xi[128][68];
    __shared__ __align__(16) float xj[128][68];
    const int b  = blockIdx.z;
    const int bi = blockIdx.x * 128;
    const int bj = blockIdx.y * 128;
    const int t  = threadIdx.x;
    const int tx = t & 15, ty = t >> 4;
    const int CP4 = CP / 4;
    const long base = (long)b * N;
    const float4* xp = (const float4*)x;

    float acc[8][8] = {};

    for (int c0 = 0; c0 < C; c0 += 64){
        const int KCc = (C - c0 < 64) ? (C - c0) : 64;
        const int KC4 = KCc >> 2;
        __syncthreads();
        for (int f = t; f < 128 * KC4; f += 256){
            int r = f / KC4, c4 = f - r * KC4;
            float4 a = xp[(base + bi + r) * CP4 + (c0 >> 2) + c4];
            float4 bv = xp[(base + bj + r) * CP4 + (c0 >> 2) + c4];
            *(float4*)&xi[r][c4 * 4] = a;
            *(float4*)&xj[r][c4 * 4] = bv;
        }
        __syncthreads();
        for (int c = 0; c < KCc; c += 4){
            float4 A[8], Bv[8];
            #pragma unroll
            for (int ii = 0; ii < 8; ++ii) A[ii]  = *(const float4*)&xi[ty + 16*ii][c];
            #pragma unroll
            for (int jj = 0; jj < 8; ++jj) Bv[jj] = *(const float4*)&xj[tx + 16*jj][c];
            #pragma unroll
            for (int ii = 0; ii < 8; ++ii)
                #pragma unroll
                for (int jj = 0; jj < 8; ++jj){
                    acc[ii][jj] = fmaf(A[ii].x, Bv[jj].x, acc[ii][jj]);
                    acc[ii][jj] = fmaf(A[ii].y, Bv[jj].y, acc[ii][jj]);
                    acc[ii][jj] = fmaf(A[ii].z, Bv[jj].z, acc[ii][jj]);
                    acc[ii][jj] = fmaf(A[ii].w, Bv[jj].w, acc[ii][jj]);
                }
        }
    }

    #pragma unroll
    for (int ii = 0; ii < 8; ++ii){
        long rbase = (base + bi + ty + 16*ii) * N + bj;
        #pragma unroll
        for (int jj = 0; jj < 8; ++jj)
            G[rbase + tx + 16*jj] = acc[ii][jj];
    }
}

// Per-row top-20 by v_j = 2*G[i][j] - sq[j]; candidates in registers.
__global__ __launch_bounds__(256) void topk_kernel(
    const float* __restrict__ G, const float* __restrict__ sq,
    int N, int* __restrict__ idx_out)
{
    __shared__ float wv_[4];
    __shared__ int   wj_[4];
    __shared__ int   gj_;
    const int row = blockIdx.x;
    const int b   = row / N;
    const int t   = threadIdx.x;
    const float* g   = G  + (long)row * N;
    const float* sqb = sq + (long)b * N;

    float v[16];
    #pragma unroll
    for (int q = 0; q < 16; ++q){
        int j = t + 256 * q;
        v[q] = fmaf(2.f, g[j], -sqb[j]);
    }
    float lv = v[0]; int lj = t;
    #pragma unroll
    for (int q = 1; q < 16; ++q)
        if (v[q] > lv){ lv = v[q]; lj = t + 256 * q; }

    for (int it = 0; it < KNN; ++it){
        float bv = lv; int bj = lj;
        #pragma unroll
        for (int off = 32; off; off >>= 1){
            float ov = __shfl_xor(bv, off);
            int   oj = __shfl_xor(bj, off);
            if (ov > bv || (ov == bv && oj < bj)){ bv = ov; bj = oj; }
        }
        if ((t & 63) == 0){ wv_[t >> 6] = bv; wj_[t >> 6] = bj; }
        __syncthreads();
        if (t == 0){
            float fv = wv_[0]; int fj = wj_[0];
            #pragma unroll
            for (int w = 1; w < 4; ++w)
                if (wv_[w] > fv || (wv_[w] == fv && wj_[w] < fj)){ fv = wv_[w]; fj = wj_[w]; }
            gj_ = fj;
            idx_out[(long)row * KNN + it] = fj;
        }
        __syncthreads();
        int fj = gj_;
        if ((fj & 255) == t){
            int q = fj >> 8;
            #pragma unroll
            for (int qq = 0; qq < 16; ++qq)
                if (qq == q) v[qq] = -INFINITY;
            lv = v[0]; lj = t;
            #pragma unroll
            for (int qq = 1; qq < 16; ++qq)
                if (v[qq] > lv){ lv = v[qq]; lj = t + 256 * qq; }
        }
    }
}

// ---------------- EdgeConv as P/Q GEMM + gather-max ----------------

// Wcat[c][n] = (c<C) ? (n<D ? W1[c][n] : W2[c][n-D]-W1[c][n-D]) : 0;  [CP][2D]
__global__ void prep_wcat_kernel(const float* __restrict__ W, int C, int CP, int D,
                                 float* __restrict__ Wcat)
{
    int i = blockIdx.x * 256 + threadIdx.x;
    int TWOD = 2 * D;
    if (i >= CP * TWOD) return;
    int c = i / TWOD, n = i - c * TWOD;
    float v = 0.f;
    if (c < C) v = (n < D) ? W[c*D + n] : (W[(C + c)*D + (n - D)] - W[c*D + (n - D)]);
    Wcat[i] = v;
}

// PQ[r][n] = (X @ Wcat)[r][n] scaled: n<D -> *g'[n] (P'); n>=D -> *g'[n-D]+b (Q')
__global__ __launch_bounds__(256) void gemm_pq_kernel(
    const float* __restrict__ X, int CP, const float* __restrict__ Wcat,
    const float* __restrict__ g, const float* __restrict__ bias,
    int D, int TWOD, float* __restrict__ PQ)
{
    __shared__ __align__(16) float As[128][68];
    __shared__ __align__(16) float Bs[64][132];
    const int bi = blockIdx.x * 128;
    const int bn = blockIdx.y * 128;
    const int t  = threadIdx.x;
    const int tx = t & 15, ty = t >> 4;
    const int CP4 = CP / 4;
    const float4* xp = (const float4*)X;

    float acc[8][8] = {};

    for (int c0 = 0; c0 < CP; c0 += 64){
        const int KC = (CP - c0 < 64) ? (CP - c0) : 64;
        const int KC4 = KC >> 2;
        __syncthreads();
        for (int f = t; f < 128 * KC4; f += 256){
            int r = f / KC4, c4 = f - r * KC4;
            *(float4*)&As[r][c4 * 4] = xp[(long)(bi + r) * CP4 + (c0 >> 2) + c4];
        }
        for (int f = t; f < KC * 32; f += 256){
            int r = f >> 5, c4 = f & 31;
            *(float4*)&Bs[r][c4 * 4] = *(const float4*)&Wcat[(long)(c0 + r) * TWOD + bn + c4 * 4];
        }
        __syncthreads();
        for (int c = 0; c < KC; c += 4){
            float4 A[8];
            #pragma unroll
            for (int ii = 0; ii < 8; ++ii) A[ii] = *(const float4*)&As[ty + 16*ii][c];
            float Bv0[8], Bv1[8], Bv2[8], Bv3[8];
            #pragma unroll
            for (int jj = 0; jj < 8; ++jj){
                Bv0[jj] = Bs[c+0][tx + 16*jj];
                Bv1[jj] = Bs[c+1][tx + 16*jj];
                Bv2[jj] = Bs[c+2][tx + 16*jj];
                Bv3[jj] = Bs[c+3][tx + 16*jj];
            }
            #pragma unroll
            for (int ii = 0; ii < 8; ++ii)
                #pragma unroll
                for (int jj = 0; jj < 8; ++jj){
                    acc[ii][jj] = fmaf(A[ii].x, Bv0[jj], acc[ii][jj]);
                    acc[ii][jj] = fmaf(A[ii].y, Bv1[jj], acc[ii][jj]);
                    acc[ii][jj] = fmaf(A[ii].z, Bv2[jj], acc[ii][jj]);
                    acc[ii][jj] = fmaf(A[ii].w, Bv3[jj], acc[ii][jj]);
                }
        }
    }

    #pragma unroll
    for (int jj = 0; jj < 8; ++jj){
        int n = bn + tx + 16*jj;
        int d = (n < D) ? n : n - D;
        float gg = g[d] * BN_INV;
        float bb = (n < D) ? 0.f : bias[d];
        #pragma unroll
        for (int ii = 0; ii < 8; ++ii)
            PQ[(long)(bi + ty + 16*ii) * TWOD + n] = fmaf(acc[ii][jj], gg, bb);
    }
}

// y[i][d] = leaky(max_{j in knn(i)} P'[j][d] + Q'[i][d]); fused sq(y) for next layer.
template<int D, int RPB>
__global__ __launch_bounds__(256) void gather_max_kernel(
    const float* __restrict__ PQ, const int* __restrict__ idx, int N,
    float* __restrict__ y, float* __restrict__ sqout)
{
    __shared__ int   lidx[RPB][KNN];
    __shared__ float sred[4];
    const int rb = blockIdx.x * RPB;
    const int t  = threadIdx.x;
    if (t < RPB * KNN) lidx[t / KNN][t % KNN] = idx[(long)rb * KNN + t];
    __syncthreads();

    const int r = t / D, d = t - r * D;
    const int row = rb + r;
    const long base = (long)(row / N) * N;
    const int TWOD = 2 * D;

    float q = PQ[(long)row * TWOD + D + d];
    float m = -INFINITY;
    #pragma unroll
    for (int k = 0; k < KNN; ++k){
        int j = lidx[r][k];
        m = fmaxf(m, PQ[(base + j) * TWOD + d]);
    }
    float val = leaky(m + q);
    y[(long)row * D + d] = val;

    float ss = val * val;
    #pragma unroll
    for (int off = 32; off; off >>= 1) ss += __shfl_xor(ss, off);
    if ((t & 63) == 0) sred[t >> 6] = ss;
    __syncthreads();
    if (d == 0){
        constexpr int WPR = D / 64;
        float s = 0.f;
        int w0 = (r * D) >> 6;
        #pragma unroll
        for (int w = 0; w < WPR; ++w) s += sred[w0 + w];
        sqout[row] = s;
    }
}

// ---------------- fallback kNN + EdgeConv (known-good) ----------------
__global__ __launch_bounds__(256) void knn_kernel(
    const float* __restrict__ x, int N, int CP4, int* __restrict__ idx_out)
{
    __shared__ float4 xi4[32];
    __shared__ float drow[4096];
    __shared__ float rv[4];
    __shared__ int   ri[4];

    int row = blockIdx.x;
    int b = row / N;
    int t = threadIdx.x;
    const float4* xp = (const float4*)x;

    if (t < CP4) xi4[t] = xp[(long)row * CP4 + t];
    __syncthreads();

    long bb = (long)b * N * CP4;
    for (int j = t; j < N; j += 256){
        const float4* p = xp + bb + (long)j * CP4;
        float acc = 0.f;
        #pragma unroll 4
        for (int c = 0; c < CP4; ++c){
            float4 xv = p[c], yv = xi4[c];
            float dx = xv.x - yv.x, dy = xv.y - yv.y;
            float dz = xv.z - yv.z, dw = xv.w - yv.w;
            acc += dx*dx + dy*dy + dz*dz + dw*dw;
        }
        drow[j] = -acc;
    }
    __syncthreads();

    for (int it = 0; it < KNN; ++it){
        float bv = -INFINITY; int bi = N;
        for (int j = t; j < N; j += 256){
            float v = drow[j];
            if (v > bv){ bv = v; bi = j; }
        }
        #pragma unroll
        for (int off = 32; off > 0; off >>= 1){
            float ov = __shfl_xor(bv, off);
            int   oi = __shfl_xor(bi, off);
            if (ov > bv || (ov == bv && oi < bi)){ bv = ov; bi = oi; }
        }
        if ((t & 63) == 0){ rv[t >> 6] = bv; ri[t >> 6] = bi; }
        __syncthreads();
        if (t == 0){
            float fv = rv[0]; int fi = ri[0];
            #pragma unroll
            for (int w = 1; w < 4; ++w){
                if (rv[w] > fv || (rv[w] == fv && ri[w] < fi)){ fv = rv[w]; fi = ri[w]; }
            }
            idx_out[(long)row * KNN + it] = fi;
            drow[fi] = -INFINITY;
        }
        __syncthreads();
    }
}

template<int D, int KPT>
__global__ __launch_bounds__(256) void edge_conv_kernel(
    const float* __restrict__ x, int N, int C, int CP,
    const float* __restrict__ W, const float* __restrict__ g,
    const float* __restrict__ bias, const int* __restrict__ idx,
    float* __restrict__ y, float* __restrict__ sqout)
{
    __shared__ float xi[128];
    __shared__ float nbr[KNN * 128];
    __shared__ float t2[D];
    __shared__ unsigned um[D];
    __shared__ float sred[4];

    int row = blockIdx.x;
    int b = row / N;
    int t = threadIdx.x;

    for (int c = t; c < C; c += 256) xi[c] = x[(long)row * CP + c];
    for (int kk = 0; kk < KNN; ++kk){
        int j = idx[(long)row * KNN + kk];
        long nb = ((long)b * N + j) * CP;
        for (int c = t; c < C; c += 256) nbr[kk * C + c] = x[nb + c];
    }
    __syncthreads();

    for (int d = t; d < D; d += 256){
        float s = 0.f;
        for (int c = 0; c < C; ++c) s += xi[c] * W[(C + c) * D + d];
        t2[d] = s; um[d] = 0u;
    }
    __syncthreads();

    const int d  = t % D;
    const int kg = t / D;
    float s[KPT];
    #pragma unroll
    for (int q = 0; q < KPT; ++q) s[q] = t2[d];

    const float* nb0 = &nbr[(kg * KPT) * C];
    for (int c = 0; c < C; ++c){
        float w   = W[c * D + d];
        float xic = xi[c];
        #pragma unroll
        for (int q = 0; q < KPT; ++q)
            s[q] += (nb0[q * C + c] - xic) * w;
    }
    float g_ = g[d] * BN_INV, b_ = bias[d];
    float m = -INFINITY;
    #pragma unroll
    for (int q = 0; q < KPT; ++q)
        m = fmaxf(m, leaky(s[q] * g_ + b_));
    atomicMax(&um[d], f2o(m));
    __syncthreads();

    float ss = 0.f;
    for (int dd = t; dd < D; dd += 256){
        float val = o2f(um[dd]);
        y[(long)row * D + dd] = val;
        ss += val * val;
    }
    #pragma unroll
    for (int off = 32; off; off >>= 1) ss += __shfl_xor(ss, off);
    if ((t & 63) == 0) sred[t >> 6] = ss;
    __syncthreads();
    if (t == 0) sqout[row] = sred[0] + sred[1] + sred[2] + sred[3];
}

// Head (unchanged)
__global__ __launch_bounds__(128) void head_kernel(
    const float* __restrict__ x1, const float* __restrict__ x2,
    const float* __restrict__ x3, const float* __restrict__ x4,
    const float* __restrict__ feats,
    const float* __restrict__ Wc5, const float* __restrict__ g5, const float* __restrict__ b5,
    const float* __restrict__ Wo1, const float* __restrict__ bo1,
    const float* __restrict__ lg1, const float* __restrict__ lb1,
    const float* __restrict__ Wo2, const float* __restrict__ bo2,
    const float* __restrict__ lg2, const float* __restrict__ lb2,
    const float* __restrict__ Wo3, const float* __restrict__ bo3,
    float* __restrict__ out, int N)
{
    __shared__ float cat[512];
    __shared__ float a[128];
    __shared__ float red[128];
    __shared__ float stats[2];

    int row = blockIdx.x;
    int t = threadIdx.x;

    cat[t]       = (t < 64) ? x1[(long)row*64 + t] : x2[(long)row*64 + (t-64)];
    cat[128 + t] = x3[(long)row*128 + t];
    cat[256 + t] = x4[(long)row*256 + t];
    cat[384 + t] = x4[(long)row*256 + 128 + t];
    __syncthreads();

    float s = 0.f;
    for (int c = 0; c < 512; ++c) s += cat[c] * Wc5[c*128 + t];
    a[t] = leaky(s * g5[t] * BN_INV + b5[t]);
    __syncthreads();

    for (int layer = 0; layer < 2; ++layer){
        const float* W  = layer ? Wo2 : Wo1;
        const float* bo = layer ? bo2 : bo1;
        const float* lg = layer ? lg2 : lg1;
        const float* lb = layer ? lb2 : lb1;
        s = bo[t];
        for (int c = 0; c < 128; ++c) s += a[c] * W[c*128 + t];
        red[t] = s; __syncthreads();
        for (int st = 64; st > 0; st >>= 1){
            if (t < st) red[t] += red[t + st];
            __syncthreads();
        }
        if (t == 0) stats[0] = red[0] * (1.f/128.f);
        __syncthreads();
        float m = stats[0];
        float dm = s - m;
        red[t] = dm * dm; __syncthreads();
        for (int st = 64; st > 0; st >>= 1){
            if (t < st) red[t] += red[t + st];
            __syncthreads();
        }
        if (t == 0) stats[1] = red[0] * (1.f/128.f);
        __syncthreads();
        float var = stats[1];
        float hn = leaky(dm * rsqrtf(var + 1e-5f) * lg[t] + lb[t]);
        __syncthreads();
        a[t] = hn;
        __syncthreads();
    }

    if (t < 38){
        float o = bo3[t];
        for (int c = 0; c < 128; ++c) o += a[c] * Wo3[c*38 + t];
        if (t < 14) o += feats[(long)row*116 + t];
        out[(long)row*38 + t] = o;
    }
}

extern "C" void kernel_launch(void* const* d_in, const int* in_sizes, int n_in,
                              void* d_out, int out_size, void* d_ws, size_t ws_size,
                              hipStream_t stream)
{
    const float* xyz  = (const float*)d_in[0];
    const float* scal = (const float*)d_in[1];
    const float* rot  = (const float*)d_in[2];
    const float* opac = (const float*)d_in[3];
    const float* colr = (const float*)d_in[4];
    const float* pose = (const float*)d_in[5];
    const float* lbs  = (const float*)d_in[6];
    const float* Wc1 = (const float*)d_in[7];  const float* g1 = (const float*)d_in[8];  const float* b1 = (const float*)d_in[9];
    const float* Wc2 = (const float*)d_in[10]; const float* g2 = (const float*)d_in[11]; const float* b2 = (const float*)d_in[12];
    const float* Wc3 = (const float*)d_in[13]; const float* g3 = (const float*)d_in[14]; const float* b3 = (const float*)d_in[15];
    const float* Wc4 = (const float*)d_in[16]; const float* g4 = (const float*)d_in[17]; const float* b4 = (const float*)d_in[18];
    const float* Wc5 = (const float*)d_in[19]; const float* g5 = (const float*)d_in[20]; const float* b5 = (const float*)d_in[21];
    const float* Wo1 = (const float*)d_in[22]; const float* bo1 = (const float*)d_in[23];
    const float* lg1 = (const float*)d_in[24]; const float* lb1 = (const float*)d_in[25];
    const float* Wo2 = (const float*)d_in[26]; const float* bo2 = (const float*)d_in[27];
    const float* lg2 = (const float*)d_in[28]; const float* lb2 = (const float*)d_in[29];
    const float* Wo3 = (const float*)d_in[30]; const float* bo3 = (const float*)d_in[31];

    const int N = in_sizes[0] / 3;      // 4096
    const int B = in_sizes[5] / 75;     // 2
    const int R = B * N;

    char* ws = (char*)d_ws;
    size_t o = 0;
    float* feats = (float*)(ws + o); o += (size_t)R * 116 * 4;
    float* x1    = (float*)(ws + o); o += (size_t)R * 64  * 4;
    float* x2    = (float*)(ws + o); o += (size_t)R * 64  * 4;
    float* x3    = (float*)(ws + o); o += (size_t)R * 128 * 4;
    float* x4    = (float*)(ws + o); o += (size_t)R * 256 * 4;
    int*   idx   = (int*)  (ws + o); o += (size_t)R * KNN * 4;
    float* sq    = (float*)(ws + o); o += (size_t)R * 4;
    float* Wcat  = (float*)(ws + o); o += (size_t)128 * 512 * 4;
    float* G     = (float*)(ws + o);
    float* PQ    = G;                   // alias: stream-ordered reuse (topk done before gemm_pq writes)
    size_t need  = o + (size_t)B * N * N * 4;

    const bool fast = (N == 4096) && (ws_size >= need);

    build_feats_kernel<<<R, 128, 0, stream>>>(xyz, scal, rot, opac, colr, pose, lbs, feats, sq, N);

    if (fast){
        dim3 gg(N/128, N/128, B);

        // L1: C=113 (CP=116), D=64
        dist_gemm_kernel<116><<<gg, 256, 0, stream>>>(feats, N, 116, G);
        topk_kernel<<<R, 256, 0, stream>>>(G, sq, N, idx);
        prep_wcat_kernel<<<(116*128 + 255)/256, 256, 0, stream>>>(Wc1, 113, 116, 64, Wcat);
        gemm_pq_kernel<<<dim3(R/128, 1), 256, 0, stream>>>(feats, 116, Wcat, g1, b1, 64, 128, PQ);
        gather_max_kernel<64, 4><<<R/4, 256, 0, stream>>>(PQ, idx, N, x1, sq);

        // L2: C=64, D=64
        dist_gemm_kernel<64><<<gg, 256, 0, stream>>>(x1, N, 64, G);
        topk_kernel<<<R, 256, 0, stream>>>(G, sq, N, idx);
        prep_wcat_kernel<<<(64*128 + 255)/256, 256, 0, stream>>>(Wc2, 64, 64, 64, Wcat);
        gemm_pq_kernel<<<dim3(R/128, 1), 256, 0, stream>>>(x1, 64, Wcat, g2, b2, 64, 128, PQ);
        gather_max_kernel<64, 4><<<R/4, 256, 0, stream>>>(PQ, idx, N, x2, sq);

        // L3: C=64, D=128
        dist_gemm_kernel<64><<<gg, 256, 0, stream>>>(x2, N, 64, G);
        topk_kernel<<<R, 256, 0, stream>>>(G, sq, N, idx);
        prep_wcat_kernel<<<(64*256 + 255)/256, 256, 0, stream>>>(Wc3, 64, 64, 128, Wcat);
        gemm_pq_kernel<<<dim3(R/128, 2), 256, 0, stream>>>(x2, 64, Wcat, g3, b3, 128, 256, PQ);
        gather_max_kernel<128, 2><<<R/2, 256, 0, stream>>>(PQ, idx, N, x3, sq);

        // L4: C=128, D=256
        dist_gemm_kernel<128><<<gg, 256, 0, stream>>>(x3, N, 128, G);
        topk_kernel<<<R, 256, 0, stream>>>(G, sq, N, idx);
        prep_wcat_kernel<<<(128*512 + 255)/256, 256, 0, stream>>>(Wc4, 128, 128, 256, Wcat);
        gemm_pq_kernel<<<dim3(R/128, 4), 256, 0, stream>>>(x3, 128, Wcat, g4, b4, 256, 512, PQ);
        gather_max_kernel<256, 1><<<R, 256, 0, stream>>>(PQ, idx, N, x4, sq);
    } else {
        knn_kernel<<<R, 256, 0, stream>>>(feats, N, 116/4, idx);
        edge_conv_kernel<64, 5><<<R, 256, 0, stream>>>(feats, N, 113, 116, Wc1, g1, b1, idx, x1, sq);
        knn_kernel<<<R, 256, 0, stream>>>(x1, N, 64/4, idx);
        edge_conv_kernel<64, 5><<<R, 256, 0, stream>>>(x1, N, 64, 64, Wc2, g2, b2, idx, x2, sq);
        knn_kernel<<<R, 256, 0, stream>>>(x2, N, 64/4, idx);
        edge_conv_kernel<128, 10><<<R, 256, 0, stream>>>(x2, N, 64, 64, Wc3, g3, b3, idx, x3, sq);
        knn_kernel<<<R, 256, 0, stream>>>(x3, N, 128/4, idx);
        edge_conv_kernel<256, 20><<<R, 256, 0, stream>>>(x3, N, 128, 128, Wc4, g4, b4, idx, x4, sq);
    }

    head_kernel<<<R, 128, 0, stream>>>(x1, x2, x3, x4, feats,
                                       Wc5, g5, b5, Wo1, bo1, lg1, lb1,
                                       Wo2, bo2, lg2, lb2, Wo3, bo3,
                                       (float*)d_out, N);
}